// Round 1
// baseline (496.520 us; speedup 1.0000x reference)
//
#include <hip/hip_runtime.h>

typedef unsigned short u16;
typedef unsigned int u32;
typedef float f32x4 __attribute__((ext_vector_type(4)));
typedef short bf16x8 __attribute__((ext_vector_type(8)));
typedef u16 u16x8 __attribute__((ext_vector_type(8)));

#define D_DIM 2048
#define HD_DIM 128
#define NCOLS 512
#define BM 128
#define HALO 16
#define MROWS 144
#define BK 32
#define KSTEPS 64
#define NTHREADS 512
#define OUT1 1048576  // 4*2048*128

#define A_STRIDE 40                          // u16 per A row (32 + 8 pad) = 80 B
#define A_BYTES (MROWS * A_STRIDE * 2)       // 11520
#define B_BYTES (NCOLS * BK * 2)             // 32768
#define OFF_A0 0
#define OFF_A1 A_BYTES
#define OFF_B0 (2 * A_BYTES)
#define OFF_B1 (OFF_B0 + B_BYTES)
#define EPI_STRIDE 520
#define SMEM_BYTES (MROWS * EPI_STRIDE * 2)  // 149760 < 160 KiB

__device__ __forceinline__ u16 f2bf(float f) {
  u32 u = __builtin_bit_cast(u32, f);
  u32 r = u + 0x7FFFu + ((u >> 16) & 1u);  // RNE (data has no NaN)
  return (u16)(r >> 16);
}
__device__ __forceinline__ float bf2f(u16 v) {
  u32 u = ((u32)v) << 16;
  return __builtin_bit_cast(float, u);
}

// Kernel 0: 4x [2048][128] f32 -> Wt = W^T [512][2048] bf16 (col-block order:
// c_a | c_b | z_a | z_b). LDS transpose, coalesced both sides.
__global__ __launch_bounds__(256) void wconv_kernel(
    const float* __restrict__ w0, const float* __restrict__ w1,
    const float* __restrict__ w2, const float* __restrict__ w3,
    u16* __restrict__ Wt) {
  __shared__ float tile[64][129];
  const int t = threadIdx.x;
  const int mat = blockIdx.x >> 5;
  const int k0 = (blockIdx.x & 31) << 6;
  const float* w = (mat == 0) ? w0 : (mat == 1) ? w1 : (mat == 2) ? w2 : w3;
#pragma unroll
  for (int i = 0; i < 32; ++i) {
    int idx = t + i * 256;
    int r = idx >> 7, c = idx & 127;
    tile[r][c] = w[(k0 + r) * HD_DIM + c];
  }
  __syncthreads();
#pragma unroll
  for (int i = 0; i < 32; ++i) {
    int idx = t + i * 256;
    int nl = idx >> 6, kk = idx & 63;
    Wt[(long)(mat * HD_DIM + nl) * D_DIM + k0 + kk] = f2bf(tile[kk][nl]);
  }
}

// Fused: per block 128 token rows (+16-row halo recompute), GEMM [144x512x2048]
// bf16 MFMA, then in-LDS window-softmax epilogue writing both output copies.
__global__ __launch_bounds__(NTHREADS, 2) void fused_kernel(
    const float* __restrict__ h, const u16* __restrict__ Wt,
    const float* __restrict__ ba, const float* __restrict__ bb,
    float* __restrict__ out) {
  __shared__ alignas(16) unsigned char smem[SMEM_BYTES];
  const int t = threadIdx.x;
  const int w = t >> 6;
  const int l = t & 63;
  const int r0 = blockIdx.x * BM;

  // ---- A staging (fp32 -> bf16): item0 = rows 0..127, item1 = halo rows 128..143
  const int arow0 = t >> 2;
  const int aseg0 = t & 3;
  const int ag0 = r0 - HALO + arow0;
  const bool av0 = (ag0 >= 0);  // zero-fill above-batch-0 halo
  const float* asrc0 = h + (long)ag0 * D_DIM + aseg0 * 8;
  const int adst0 = arow0 * A_STRIDE + aseg0 * 8;

  const bool has2 = ((t & 7) == 0);
  const int q2 = 512 + (t >> 3);
  const int arow1 = q2 >> 2;
  const int aseg1 = q2 & 3;
  const float* asrc1 = h + (long)(r0 - HALO + arow1) * D_DIM + aseg1 * 8;
  const int adst1 = arow1 * A_STRIDE + aseg1 * 8;

  // ---- B staging: [512][32] bf16 rows, 16B-chunk XOR swizzle (c ^ ((row>>1)&3))
  const int brow = t >> 2;
  const int bc = t & 3;
  const int bswz = bc ^ ((t >> 3) & 3);
  const u16* bsrc0 = Wt + (long)brow * D_DIM + bc * 8;
  const int bdst = brow * 32 + bswz * 8;

  // ---- fragment read offsets (u16 elements)
  const int aoff0 = (l & 15) * A_STRIDE + (l >> 4) * 8;
  const int swzr = (l >> 4) ^ ((l >> 1) & 3);
  const int boff0 = (w * 64 + (l & 15)) * 32 + swzr * 8;

  f32x4 acc[9][4];
#pragma unroll
  for (int mt = 0; mt < 9; ++mt)
#pragma unroll
    for (int nt = 0; nt < 4; ++nt) acc[mt][nt] = (f32x4){0.f, 0.f, 0.f, 0.f};

  float4 la0a, la0b, la1a, la1b;
  u16x8 bs0, bs1, bs2, bs3;

#define DO_LOADS(K0)                                          \
  {                                                           \
    const float4 z4 = make_float4(0.f, 0.f, 0.f, 0.f);        \
    la0a = av0 ? *(const float4*)(asrc0 + (K0)) : z4;         \
    la0b = av0 ? *(const float4*)(asrc0 + (K0) + 4) : z4;     \
    if (has2) {                                               \
      la1a = *(const float4*)(asrc1 + (K0));                  \
      la1b = *(const float4*)(asrc1 + (K0) + 4);              \
    }                                                         \
    bs0 = *(const u16x8*)(bsrc0 + (K0));                      \
    bs1 = *(const u16x8*)(bsrc0 + 128 * 2048 + (K0));         \
    bs2 = *(const u16x8*)(bsrc0 + 256 * 2048 + (K0));         \
    bs3 = *(const u16x8*)(bsrc0 + 384 * 2048 + (K0));         \
  }

#define DO_STORE(BUF)                                         \
  {                                                           \
    u16* Ab = (u16*)(smem + ((BUF) ? OFF_A1 : OFF_A0));       \
    u16* Bb = (u16*)(smem + ((BUF) ? OFF_B1 : OFF_B0));       \
    u16x8 pa;                                                 \
    pa[0] = f2bf(la0a.x); pa[1] = f2bf(la0a.y);               \
    pa[2] = f2bf(la0a.z); pa[3] = f2bf(la0a.w);               \
    pa[4] = f2bf(la0b.x); pa[5] = f2bf(la0b.y);               \
    pa[6] = f2bf(la0b.z); pa[7] = f2bf(la0b.w);               \
    *(u16x8*)(Ab + adst0) = pa;                               \
    if (has2) {                                               \
      u16x8 pb;                                               \
      pb[0] = f2bf(la1a.x); pb[1] = f2bf(la1a.y);             \
      pb[2] = f2bf(la1a.z); pb[3] = f2bf(la1a.w);             \
      pb[4] = f2bf(la1b.x); pb[5] = f2bf(la1b.y);             \
      pb[6] = f2bf(la1b.z); pb[7] = f2bf(la1b.w);             \
      *(u16x8*)(Ab + adst1) = pb;                             \
    }                                                         \
    *(u16x8*)(Bb + bdst) = bs0;                               \
    *(u16x8*)(Bb + 128 * 32 + bdst) = bs1;                    \
    *(u16x8*)(Bb + 256 * 32 + bdst) = bs2;                    \
    *(u16x8*)(Bb + 384 * 32 + bdst) = bs3;                    \
  }

  DO_LOADS(0)
  DO_STORE(0)
  __syncthreads();

  for (int step = 0; step < KSTEPS; ++step) {
    const int cur = step & 1;
    const bool more = (step + 1) < KSTEPS;
    if (more) DO_LOADS((step + 1) * BK)
    {
      const u16* Ab = (const u16*)(smem + (cur ? OFF_A1 : OFF_A0));
      const u16* Bb = (const u16*)(smem + (cur ? OFF_B1 : OFF_B0));
      bf16x8 bfr[4];
#pragma unroll
      for (int nt = 0; nt < 4; ++nt)
        bfr[nt] = *(const bf16x8*)(Bb + boff0 + nt * (16 * 32));
#pragma unroll
      for (int mt = 0; mt < 9; ++mt) {
        bf16x8 af = *(const bf16x8*)(Ab + aoff0 + mt * (16 * A_STRIDE));
#pragma unroll
        for (int nt = 0; nt < 4; ++nt)
          acc[mt][nt] = __builtin_amdgcn_mfma_f32_16x16x32_bf16(
              af, bfr[nt], acc[mt][nt], 0, 0, 0);
      }
    }
    if (more) DO_STORE(cur ^ 1)
    __syncthreads();
  }

  // ---- epilogue: dump acc (bf16) to LDS [144][520], then window softmax
  u16* E = (u16*)smem;
  {
    const int er = (l >> 4) * 4;
    const int ec = w * 64 + (l & 15);
#pragma unroll
    for (int mt = 0; mt < 9; ++mt)
#pragma unroll
      for (int nt = 0; nt < 4; ++nt)
#pragma unroll
        for (int j = 0; j < 4; ++j)
          E[(mt * 16 + er + j) * EPI_STRIDE + ec + nt * 16] =
              f2bf(acc[mt][nt][j]);
  }
  __syncthreads();

  {
    const int hd = t & 127;
    const int grp = t >> 7;
    const int b = r0 >> 13;
    const int sbase = r0 & 8191;
#pragma unroll
    for (int i = 0; i < 8; ++i) {
      const int nblk = grp * 8 + i;
      const int s_in = sbase + nblk * 4;
      const bool first = (s_in == 0);  // block 0 of a batch: mask prev half
      const int rc = HALO + nblk * 4;
      float la[4], lb[4], ca[4], cb[4];
#pragma unroll
      for (int j = 0; j < 4; ++j) {
        const u16* rowc = E + (rc + j) * EPI_STRIDE;
        const u16* rowp = E + (rc - 4 + j) * EPI_STRIDE;
        la[j] = bf2f(rowc[256 + hd]) + ba[j * 128 + hd];   // z_a + b_a
        ca[j] = bf2f(rowc[hd]);                            // c_a
        lb[j] = first ? -3.0e38f
                      : (bf2f(rowp[384 + hd]) + bb[j * 128 + hd]);  // z_b + b_b
        cb[j] = bf2f(rowp[128 + hd]);                      // c_b (prev block)
      }
      float mx = la[0];
#pragma unroll
      for (int j = 1; j < 4; ++j) mx = fmaxf(mx, la[j]);
#pragma unroll
      for (int j = 0; j < 4; ++j) mx = fmaxf(mx, lb[j]);
      float num = 0.f, den = 0.f;
#pragma unroll
      for (int j = 0; j < 4; ++j) {
        float ea = __expf(la[j] - mx);
        num += ea * ca[j]; den += ea;
        float eb = __expf(lb[j] - mx);  // -> 0 when masked
        num += eb * cb[j]; den += eb;
      }
      const float res = num / den;
      const int o = ((b << 11) + (s_in >> 2)) * HD_DIM + hd;
      out[o] = res;
      out[o + OUT1] = res;
    }
  }
}

extern "C" void kernel_launch(void* const* d_in, const int* in_sizes, int n_in,
                              void* d_out, int out_size, void* d_ws,
                              size_t ws_size, hipStream_t stream) {
  (void)in_sizes; (void)n_in; (void)out_size; (void)ws_size;
  const float* h = (const float*)d_in[0];
  const float* w_kv_a = (const float*)d_in[1];
  const float* w_kv_b = (const float*)d_in[2];
  const float* w_z_a = (const float*)d_in[3];
  const float* w_z_b = (const float*)d_in[4];
  const float* b_a = (const float*)d_in[5];
  const float* b_b = (const float*)d_in[6];
  u16* Wt = (u16*)d_ws;  // 2 MB bf16 W^T
  float* out = (float*)d_out;
  wconv_kernel<<<128, 256, 0, stream>>>(w_kv_a, w_kv_b, w_z_a, w_z_b, Wt);
  fused_kernel<<<256, NTHREADS, 0, stream>>>(h, Wt, b_a, b_b, out);
}

// Round 3
// 421.544 us; speedup vs baseline: 1.1779x; 1.1779x over previous
//
#include <hip/hip_runtime.h>

typedef unsigned short u16;
typedef unsigned int u32;
typedef float f32x4 __attribute__((ext_vector_type(4)));
typedef short bf16x8 __attribute__((ext_vector_type(8)));
typedef u16 u16x8 __attribute__((ext_vector_type(8)));

#define D_DIM 2048
#define HD_DIM 128
#define BM 128
#define HALO 16
#define MROWS 144
#define BK 32
#define KSTEPS 64
#define NTHREADS 512
#define OUT1 1048576  // 4*2048*128

#define A_STRIDE 40                     // u16 per A row (32 + 8 pad) = 80 B
#define A_BYTES (MROWS * A_STRIDE * 2)  // 11520
#define B_BYTES (512 * BK * 2)          // 32768 per buffer
#define OFF_A (3 * B_BYTES)             // A buffers after 3 B buffers
#define EPI_STRIDE 520
#define SMEM_BYTES (MROWS * EPI_STRIDE * 2)  // 149760 (>= 132864 GEMM use)

__device__ __forceinline__ u16 f2bf(float f) {
  u32 u = __builtin_bit_cast(u32, f);
  u32 r = u + 0x7FFFu + ((u >> 16) & 1u);  // RNE
  return (u16)(r >> 16);
}
__device__ __forceinline__ float bf2f(u16 v) {
  u32 u = ((u32)v) << 16;
  return __builtin_bit_cast(float, u);
}

__device__ __forceinline__ void gload_lds16(const u16* g, u16* l) {
  __builtin_amdgcn_global_load_lds(
      (const __attribute__((address_space(1))) unsigned int*)g,
      (__attribute__((address_space(3))) unsigned int*)l, 16, 0, 0);
}

// Kernel 0: 4x [2048][128] f32 -> Wt tiled per K-step: 64 tiles of 32KB,
// tile layout = swizzled LDS image: u16 pos = n*32 + ((kk>>3)^((n>>1)&3))*8 + (kk&7)
__global__ __launch_bounds__(256) void wconv_kernel(
    const float* __restrict__ w0, const float* __restrict__ w1,
    const float* __restrict__ w2, const float* __restrict__ w3,
    u16* __restrict__ Wt) {
  __shared__ float tile[64][129];
  const int t = threadIdx.x;
  const int mat = blockIdx.x >> 5;
  const int k0 = (blockIdx.x & 31) << 6;
  const float* w = (mat == 0) ? w0 : (mat == 1) ? w1 : (mat == 2) ? w2 : w3;
#pragma unroll
  for (int i = 0; i < 32; ++i) {
    int idx = t + i * 256;
    int r = idx >> 7, c = idx & 127;
    tile[r][c] = w[(k0 + r) * HD_DIM + c];
  }
  __syncthreads();
#pragma unroll
  for (int i = 0; i < 32; ++i) {
    int idx = t + i * 256;
    int nl = idx >> 6, kk = idx & 63;
    int n = mat * HD_DIM + nl;
    int k = k0 + kk;
    int stepi = k >> 5, kr = k & 31;
    int pos = stepi * 16384 + n * 32 + (((kr >> 3) ^ ((n >> 1) & 3)) << 3) + (kr & 7);
    Wt[pos] = f2bf(tile[kk][nl]);
  }
}

__global__ __launch_bounds__(NTHREADS, 2) void fused_kernel(
    const float* __restrict__ h, const u16* __restrict__ Wt,
    const float* __restrict__ ba, const float* __restrict__ bb,
    float* __restrict__ out) {
  __shared__ alignas(16) unsigned char smem[SMEM_BYTES];
  const int t = threadIdx.x;
  const int w = t >> 6;
  const int l = t & 63;
  const int r0 = blockIdx.x * BM;

  // ---- A staging mapping (fp32->bf16): rows 0..127 + halo rows 128..143
  const int arow0 = t >> 2, aseg0 = t & 3;
  const int ag0 = r0 - HALO + arow0;
  const bool av0 = (ag0 >= 0);
  const long ag0c = av0 ? (long)ag0 : 0l;  // clamp: always issue the load
  const float* asrc0 = h + ag0c * D_DIM + aseg0 * 8;
  const int adst0 = arow0 * A_STRIDE + aseg0 * 8;
  const bool has2 = ((t & 7) == 0);
  const int arow1 = 128 + (t >> 5);
  const int aseg1 = (t >> 3) & 3;
  const float* asrc1 = h + (long)(r0 - HALO + arow1) * D_DIM + aseg1 * 8;
  const int adst1 = arow1 * A_STRIDE + aseg1 * 8;

  // ---- fragment read offsets (u16 elements)
  const int aoff0 = (l & 15) * A_STRIDE + (l >> 4) * 8;
  const int swzr = (l >> 4) ^ ((l >> 1) & 3);
  const int boff0 = (w * 64 + (l & 15)) * 32 + swzr * 8;

  f32x4 acc[9][4];
#pragma unroll
  for (int mt = 0; mt < 9; ++mt)
#pragma unroll
    for (int nt = 0; nt < 4; ++nt) acc[mt][nt] = (f32x4){0.f, 0.f, 0.f, 0.f};

  float4 r0a, r0b, r0ha, r0hb, r1a, r1b, r1ha, r1hb;

// per-wave B stage: 4 x 1KB global_load_lds, tile SI -> B buffer BI
#define ISSUE_B(SI, BI)                                           \
  {                                                               \
    const u16* gsrc = Wt + (size_t)(SI) * 16384 + w * 2048 + l * 8; \
    u16* lb = (u16*)(smem + (BI) * B_BYTES) + w * 2048;           \
    gload_lds16(gsrc, lb);                                        \
    gload_lds16(gsrc + 512, lb + 512);                            \
    gload_lds16(gsrc + 1024, lb + 1024);                          \
    gload_lds16(gsrc + 1536, lb + 1536);                          \
  }

#define ISSUE_A(SI, RA, RB, RHA, RHB)      \
  {                                        \
    const float* p0 = asrc0 + (SI) * BK;   \
    RA = *(const float4*)(p0);             \
    RB = *(const float4*)(p0 + 4);         \
    if (has2) {                            \
      const float* p1 = asrc1 + (SI) * BK; \
      RHA = *(const float4*)(p1);          \
      RHB = *(const float4*)(p1 + 4);      \
    }                                      \
  }

#define WRITE_A(BI, RA, RB, RHA, RHB)                  \
  {                                                    \
    u16* Ab = (u16*)(smem + OFF_A + (BI) * A_BYTES);   \
    u16x8 pa;                                          \
    pa[0] = av0 ? f2bf(RA.x) : (u16)0;                 \
    pa[1] = av0 ? f2bf(RA.y) : (u16)0;                 \
    pa[2] = av0 ? f2bf(RA.z) : (u16)0;                 \
    pa[3] = av0 ? f2bf(RA.w) : (u16)0;                 \
    pa[4] = av0 ? f2bf(RB.x) : (u16)0;                 \
    pa[5] = av0 ? f2bf(RB.y) : (u16)0;                 \
    pa[6] = av0 ? f2bf(RB.z) : (u16)0;                 \
    pa[7] = av0 ? f2bf(RB.w) : (u16)0;                 \
    *(u16x8*)(Ab + adst0) = pa;                        \
    if (has2) {                                        \
      u16x8 pb;                                        \
      pb[0] = f2bf(RHA.x); pb[1] = f2bf(RHA.y);        \
      pb[2] = f2bf(RHA.z); pb[3] = f2bf(RHA.w);        \
      pb[4] = f2bf(RHB.x); pb[5] = f2bf(RHB.y);        \
      pb[6] = f2bf(RHB.z); pb[7] = f2bf(RHB.w);        \
      *(u16x8*)(Ab + adst1) = pb;                      \
    }                                                  \
  }

#define COMPUTE(BI)                                                         \
  {                                                                         \
    const u16* Ab = (const u16*)(smem + OFF_A + (BI) * A_BYTES);            \
    const u16* Bb = (const u16*)(smem + (BI) * B_BYTES);                    \
    bf16x8 bfr0 = *(const bf16x8*)(Bb + boff0);                             \
    bf16x8 bfr1 = *(const bf16x8*)(Bb + boff0 + 512);                       \
    bf16x8 bfr2 = *(const bf16x8*)(Bb + boff0 + 1024);                      \
    bf16x8 bfr3 = *(const bf16x8*)(Bb + boff0 + 1536);                      \
    _Pragma("unroll")                                                       \
    for (int mt = 0; mt < 9; ++mt) {                                        \
      bf16x8 af = *(const bf16x8*)(Ab + aoff0 + mt * (16 * A_STRIDE));      \
      acc[mt][0] = __builtin_amdgcn_mfma_f32_16x16x32_bf16(af, bfr0, acc[mt][0], 0, 0, 0); \
      acc[mt][1] = __builtin_amdgcn_mfma_f32_16x16x32_bf16(af, bfr1, acc[mt][1], 0, 0, 0); \
      acc[mt][2] = __builtin_amdgcn_mfma_f32_16x16x32_bf16(af, bfr2, acc[mt][2], 0, 0, 0); \
      acc[mt][3] = __builtin_amdgcn_mfma_f32_16x16x32_bf16(af, bfr3, acc[mt][3], 0, 0, 0); \
    }                                                                       \
  }

#define VM_WAIT8() asm volatile("s_waitcnt vmcnt(8)" ::: "memory")
#define VM_WAIT0() asm volatile("s_waitcnt vmcnt(0)" ::: "memory")
#define SYNC_ITER()                                        \
  {                                                        \
    asm volatile("s_waitcnt lgkmcnt(0)" ::: "memory");     \
    __builtin_amdgcn_s_barrier();                          \
  }

  // ---- prologue: groups 0 and 1 in flight; A(0) staged to LDS
  ISSUE_B(0, 0)
  ISSUE_A(0, r0a, r0b, r0ha, r0hb)
  ISSUE_B(1, 1)
  ISSUE_A(1, r1a, r1b, r1ha, r1hb)
  VM_WAIT8();  // drain group 0
  WRITE_A(0, r0a, r0b, r0ha, r0hb)
  SYNC_ITER();

  // ---- main loop, 2-unrolled (named A reg sets), buffers mod 3
  for (int s = 0; s < KSTEPS - 2; s += 2) {
    const int b0 = s % 3, b1 = (s + 1) % 3, b2 = (s + 2) % 3, b3 = (s + 3) % 3;
    // even body: consume buf b0; regs R1 hold A(s+1); prefetch s+2 into R0
    ISSUE_B(s + 2, b2)
    ISSUE_A(s + 2, r0a, r0b, r0ha, r0hb)
    VM_WAIT8();  // drain group s+1 (B(s+1) in LDS, A(s+1) in R1)
    WRITE_A(b1, r1a, r1b, r1ha, r1hb)
    COMPUTE(b0)
    SYNC_ITER();
    // odd body: consume buf b1; regs R0 hold A(s+2); prefetch s+3 into R1
    ISSUE_B(s + 3, b3)
    ISSUE_A(s + 3, r1a, r1b, r1ha, r1hb)
    VM_WAIT8();  // drain group s+2
    WRITE_A(b2, r0a, r0b, r0ha, r0hb)
    COMPUTE(b1)
    SYNC_ITER();
  }
  // ---- tail: s = 62 (R1 holds A(63) in flight), then s = 63
  VM_WAIT0();
  WRITE_A(0, r1a, r1b, r1ha, r1hb)  // 63 % 3 == 0
  COMPUTE(2)                        // 62 % 3 == 2
  SYNC_ITER();
  COMPUTE(0)
  __syncthreads();

  // ---- epilogue: dump acc (bf16) to LDS [144][520], then window softmax
  u16* E = (u16*)smem;
  {
    const int er = (l >> 4) * 4;
    const int ec = w * 64 + (l & 15);
#pragma unroll
    for (int mt = 0; mt < 9; ++mt)
#pragma unroll
      for (int nt = 0; nt < 4; ++nt)
#pragma unroll
        for (int j = 0; j < 4; ++j)
          E[(mt * 16 + er + j) * EPI_STRIDE + ec + nt * 16] =
              f2bf(acc[mt][nt][j]);
  }
  __syncthreads();

  {
    const int hd = t & 127;
    const int grp = t >> 7;
    const int b = r0 >> 13;
    const int sbase = r0 & 8191;
#pragma unroll
    for (int i = 0; i < 8; ++i) {
      const int nblk = grp * 8 + i;
      const int s_in = sbase + nblk * 4;
      const bool first = (s_in == 0);
      const int rc = HALO + nblk * 4;
      float la[4], lb[4], ca[4], cb[4];
#pragma unroll
      for (int j = 0; j < 4; ++j) {
        const u16* rowc = E + (rc + j) * EPI_STRIDE;
        const u16* rowp = E + (rc - 4 + j) * EPI_STRIDE;
        la[j] = bf2f(rowc[256 + hd]) + ba[j * 128 + hd];
        ca[j] = bf2f(rowc[hd]);
        lb[j] = first ? -3.0e38f : (bf2f(rowp[384 + hd]) + bb[j * 128 + hd]);
        cb[j] = bf2f(rowp[128 + hd]);
      }
      float mx = la[0];
#pragma unroll
      for (int j = 1; j < 4; ++j) mx = fmaxf(mx, la[j]);
#pragma unroll
      for (int j = 0; j < 4; ++j) mx = fmaxf(mx, lb[j]);
      float num = 0.f, den = 0.f;
#pragma unroll
      for (int j = 0; j < 4; ++j) {
        float ea = __expf(la[j] - mx);
        num += ea * ca[j]; den += ea;
        float eb = __expf(lb[j] - mx);
        num += eb * cb[j]; den += eb;
      }
      const float res = num / den;
      const int o = ((b << 11) + (s_in >> 2)) * HD_DIM + hd;
      out[o] = res;
      out[o + OUT1] = res;
    }
  }
}

extern "C" void kernel_launch(void* const* d_in, const int* in_sizes, int n_in,
                              void* d_out, int out_size, void* d_ws,
                              size_t ws_size, hipStream_t stream) {
  (void)in_sizes; (void)n_in; (void)out_size; (void)ws_size;
  const float* h = (const float*)d_in[0];
  const float* w_kv_a = (const float*)d_in[1];
  const float* w_kv_b = (const float*)d_in[2];
  const float* w_z_a = (const float*)d_in[3];
  const float* w_z_b = (const float*)d_in[4];
  const float* b_a = (const float*)d_in[5];
  const float* b_b = (const float*)d_in[6];
  u16* Wt = (u16*)d_ws;  // 2 MB tiled+swizzled bf16 weights
  float* out = (float*)d_out;
  wconv_kernel<<<128, 256, 0, stream>>>(w_kv_a, w_kv_b, w_z_a, w_z_b, Wt);
  fused_kernel<<<256, NTHREADS, 0, stream>>>(h, Wt, b_a, b_b, out);
}

// Round 7
// 405.524 us; speedup vs baseline: 1.2244x; 1.0395x over previous
//
#include <hip/hip_runtime.h>

typedef unsigned short u16;
typedef unsigned int u32;
typedef float f32x4 __attribute__((ext_vector_type(4)));
typedef short bf16x8 __attribute__((ext_vector_type(8)));
typedef u16 u16x8 __attribute__((ext_vector_type(8)));

#define D_DIM 2048
#define HD_DIM 128
#define BM 128
#define HALO 16
#define MROWS 144
#define BK 32
#define KSTEPS 64
#define NTHREADS 512
#define OUT1 1048576  // 4*2048*128

#define A_STRIDE 40                     // u16 per A row (32 + 8 pad) = 80 B
#define A_BYTES (MROWS * A_STRIDE * 2)  // 11520
#define SMEM_BYTES (2 * A_BYTES)        // 23040 — A double buffer only

__device__ __forceinline__ u16 f2bf(float f) {
  u32 u = __builtin_bit_cast(u32, f);
  u32 r = u + 0x7FFFu + ((u >> 16) & 1u);  // RNE
  return (u16)(r >> 16);
}

// Kernel 0: 4x [2048][128] f32 -> Wt in MFMA-fragment-ready order:
// element (n, k): s=k>>5, slot=(k>>3)&3, off=k&7, n = mat*128 + col
// pos = ((s*4 + slot)*512 + n)*8 + off   (16B per lane-frag, frag-contiguous)
__global__ __launch_bounds__(256) void wconv_kernel(
    const float* __restrict__ w0, const float* __restrict__ w1,
    const float* __restrict__ w2, const float* __restrict__ w3,
    u16* __restrict__ Wt) {
  __shared__ float tile[64][129];
  const int t = threadIdx.x;
  const int mat = blockIdx.x >> 5;
  const int k0 = (blockIdx.x & 31) << 6;
  const float* w = (mat == 0) ? w0 : (mat == 1) ? w1 : (mat == 2) ? w2 : w3;
#pragma unroll
  for (int i = 0; i < 32; ++i) {
    int idx = t + i * 256;
    int r = idx >> 7, c = idx & 127;
    tile[r][c] = w[(k0 + r) * HD_DIM + c];
  }
  __syncthreads();
#pragma unroll
  for (int i = 0; i < 32; ++i) {
    int idx = t + i * 256;
    int nl = idx >> 6, kk = idx & 63;
    int n = mat * HD_DIM + nl;
    int k = k0 + kk;
    int s = k >> 5, slot = (k >> 3) & 3, off = k & 7;
    Wt[(size_t)((s * 4 + slot) * 512 + n) * 8 + off] = f2bf(tile[kk][nl]);
  }
}

__global__ __launch_bounds__(NTHREADS, 2) void fused_kernel(
    const float* __restrict__ h, const u16* __restrict__ Wt,
    const float* __restrict__ ba, const float* __restrict__ bb,
    float* __restrict__ out) {
  __shared__ alignas(16) unsigned char smem[SMEM_BYTES];
  const int t = threadIdx.x;
  const int w = t >> 6;
  const int l = t & 63;
  const int r0 = blockIdx.x * BM;

  // ---- A staging map (fp32->bf16): LDS row i <-> global row r0-16+i, i=0..143
  const int arow0 = t >> 2, aseg0 = t & 3;
  const int ag0 = r0 - HALO + arow0;
  const bool av0 = (ag0 >= 0);
  const long ag0c = av0 ? (long)ag0 : 0l;  // clamp: always issue the load
  const float* asrc0 = h + ag0c * D_DIM + aseg0 * 8;
  const int adst0 = arow0 * A_STRIDE + aseg0 * 8;
  const bool has2 = ((t & 7) == 0);
  const int arow1 = 128 + (t >> 5);
  const int aseg1 = (t >> 3) & 3;
  const float* asrc1 = h + (long)(r0 - HALO + arow1) * D_DIM + aseg1 * 8;
  const int adst1 = arow1 * A_STRIDE + aseg1 * 8;

  // ---- fragment offsets
  const int aoff0 = (l & 15) * A_STRIDE + (l >> 4) * 8;  // u16
  const int lb_base = ((l >> 4) * 512 + w * 16 + (l & 15)) * 8;  // u16, B frag

  f32x4 acc[9][4];
#pragma unroll
  for (int mt = 0; mt < 9; ++mt)
#pragma unroll
    for (int p = 0; p < 4; ++p) acc[mt][p] = (f32x4){0.f, 0.f, 0.f, 0.f};

  float4 r0a, r0b, r0ha, r0hb, r1a, r1b, r1ha, r1hb;
  bf16x8 B0[4], B1[4];

#define ISSUE_B(SI, BARR)                                  \
  {                                                        \
    const u16* gp = Wt + (size_t)(SI) * 16384 + lb_base;   \
    BARR[0] = *(const bf16x8*)(gp);                        \
    BARR[1] = *(const bf16x8*)(gp + 1024);                 \
    BARR[2] = *(const bf16x8*)(gp + 2048);                 \
    BARR[3] = *(const bf16x8*)(gp + 3072);                 \
  }

#define ISSUE_A(SI, RA, RB, RHA, RHB)      \
  {                                        \
    const float* p0 = asrc0 + (SI) * BK;   \
    RA = *(const float4*)(p0);             \
    RB = *(const float4*)(p0 + 4);         \
    if (has2) {                            \
      const float* p1 = asrc1 + (SI) * BK; \
      RHA = *(const float4*)(p1);          \
      RHB = *(const float4*)(p1 + 4);      \
    }                                      \
  }

#define WRITE_A(BI, RA, RB, RHA, RHB)            \
  {                                              \
    u16* Ab = (u16*)(smem + (BI) * A_BYTES);     \
    u16x8 pa;                                    \
    pa[0] = av0 ? f2bf(RA.x) : (u16)0;           \
    pa[1] = av0 ? f2bf(RA.y) : (u16)0;           \
    pa[2] = av0 ? f2bf(RA.z) : (u16)0;           \
    pa[3] = av0 ? f2bf(RA.w) : (u16)0;           \
    pa[4] = av0 ? f2bf(RB.x) : (u16)0;           \
    pa[5] = av0 ? f2bf(RB.y) : (u16)0;           \
    pa[6] = av0 ? f2bf(RB.z) : (u16)0;           \
    pa[7] = av0 ? f2bf(RB.w) : (u16)0;           \
    *(u16x8*)(Ab + adst0) = pa;                  \
    if (has2) {                                  \
      u16x8 pb;                                  \
      pb[0] = f2bf(RHA.x); pb[1] = f2bf(RHA.y);  \
      pb[2] = f2bf(RHA.z); pb[3] = f2bf(RHA.w);  \
      pb[4] = f2bf(RHB.x); pb[5] = f2bf(RHB.y);  \
      pb[6] = f2bf(RHB.z); pb[7] = f2bf(RHB.w);  \
      *(u16x8*)(Ab + adst1) = pb;                \
    }                                            \
  }

#define COMPUTE(BI, BARR)                                                   \
  {                                                                         \
    const u16* Ab = (const u16*)(smem + (BI) * A_BYTES);                    \
    _Pragma("unroll")                                                       \
    for (int mt = 0; mt < 9; ++mt) {                                        \
      bf16x8 af = *(const bf16x8*)(Ab + aoff0 + mt * (16 * A_STRIDE));      \
      acc[mt][0] = __builtin_amdgcn_mfma_f32_16x16x32_bf16(af, BARR[0], acc[mt][0], 0, 0, 0); \
      acc[mt][1] = __builtin_amdgcn_mfma_f32_16x16x32_bf16(af, BARR[1], acc[mt][1], 0, 0, 0); \
      acc[mt][2] = __builtin_amdgcn_mfma_f32_16x16x32_bf16(af, BARR[2], acc[mt][2], 0, 0, 0); \
      acc[mt][3] = __builtin_amdgcn_mfma_f32_16x16x32_bf16(af, BARR[3], acc[mt][3], 0, 0, 0); \
    }                                                                       \
  }

// raw barrier: ds_writes drained via lgkm(0); VMEM loads (reg-dest) stay in
// flight across the barrier — compiler inserts precise vmcnt at first use.
#define SYNC_ITER()                                    \
  {                                                    \
    asm volatile("s_waitcnt lgkmcnt(0)" ::: "memory"); \
    __builtin_amdgcn_s_barrier();                      \
  }

  // ---- prologue: buf0 = A(0); R1 = A(1); B0 = B(0) (in flight)
  ISSUE_A(0, r0a, r0b, r0ha, r0hb)
  ISSUE_B(0, B0)
  ISSUE_A(1, r1a, r1b, r1ha, r1hb)
  WRITE_A(0, r0a, r0b, r0ha, r0hb)
  SYNC_ITER();

  // ---- main loop: computes steps 0..61 (2-unrolled; invariant at head of
  // iteration s: buf(s&1)=A(s), R1=A(s+1), B0=B(s))
  for (int s = 0; s < KSTEPS - 2; s += 2) {
    // even body: compute step s (buf s&1, regs B0); A(s+1) in R1
    ISSUE_B(s + 1, B1)
    ISSUE_A(s + 2, r0a, r0b, r0ha, r0hb)
    COMPUTE(s & 1, B0)
    WRITE_A((s + 1) & 1, r1a, r1b, r1ha, r1hb)
    SYNC_ITER();
    // odd body: compute step s+1 (buf (s+1)&1, regs B1); A(s+2) in R0
    ISSUE_B(s + 2, B0)
    ISSUE_A(s + 3, r1a, r1b, r1ha, r1hb)
    COMPUTE((s + 1) & 1, B1)
    WRITE_A(s & 1, r0a, r0b, r0ha, r0hb)
    SYNC_ITER();
  }
  // ---- tail: loop exit state buf0=A(62), R1=A(63), B0=B(62)
  ISSUE_B(63, B1)
  COMPUTE(0, B0)                    // step 62
  WRITE_A(1, r1a, r1b, r1ha, r1hb)  // A(63) -> buf1
  SYNC_ITER();
  COMPUTE(1, B1)                    // step 63

  // ---- epilogue: fully in-register window softmax (no LDS, no barrier)
  // lane l (group g=l>>4) holds rows mt*16+g*4+j, col hd=w*16+(l&15),
  // acc[mt][p]: p = 0:c_a 1:c_b 2:z_a 3:z_b
  {
    const int g = l >> 4;
    const int hd = (w << 4) + (l & 15);
    const int src = (l + 48) & 63;  // lane-rotate: group g-1 (g=0 -> group 3)
    float ba_r[4], bb_r[4];
#pragma unroll
    for (int j = 0; j < 4; ++j) {
      ba_r[j] = ba[j * HD_DIM + hd];
      bb_r[j] = bb[j * HD_DIM + hd];
    }
    const int b = r0 >> 13;
    const int sbase = r0 & 8191;
    const bool firstBlk = (sbase == 0);
#pragma unroll
    for (int mt = 1; mt <= 8; ++mt) {
      const bool mask0 = firstBlk && (mt == 1) && (g == 0);
      float la[4], lb[4], ca[4], cb[4];
#pragma unroll
      for (int j = 0; j < 4; ++j) {
        la[j] = acc[mt][2][j] + ba_r[j];
        ca[j] = acc[mt][0][j];
        float zb_s = __shfl(acc[mt][3][j], src, 64);
        float zb_p = __shfl(acc[mt - 1][3][j], src, 64);
        float cb_s = __shfl(acc[mt][1][j], src, 64);
        float cb_p = __shfl(acc[mt - 1][1][j], src, 64);
        float zb = (g == 0) ? zb_p : zb_s;
        cb[j] = (g == 0) ? cb_p : cb_s;
        lb[j] = mask0 ? -3.0e38f : (zb + bb_r[j]);
      }
      float mx = la[0];
#pragma unroll
      for (int j = 1; j < 4; ++j) mx = fmaxf(mx, la[j]);
#pragma unroll
      for (int j = 0; j < 4; ++j) mx = fmaxf(mx, lb[j]);
      float num = 0.f, den = 0.f;
#pragma unroll
      for (int j = 0; j < 4; ++j) {
        float ea = __expf(la[j] - mx);
        num += ea * ca[j]; den += ea;
        float eb = __expf(lb[j] - mx);
        num += eb * cb[j]; den += eb;
      }
      const float res = num / den;
      const int nblk = (sbase >> 2) + (mt - 1) * 4 + g;
      const int o = ((b << 11) + nblk) * HD_DIM + hd;
      out[o] = res;
      out[o + OUT1] = res;
    }
  }
}

extern "C" void kernel_launch(void* const* d_in, const int* in_sizes, int n_in,
                              void* d_out, int out_size, void* d_ws,
                              size_t ws_size, hipStream_t stream) {
  (void)in_sizes; (void)n_in; (void)out_size; (void)ws_size;
  const float* h = (const float*)d_in[0];
  const float* w_kv_a = (const float*)d_in[1];
  const float* w_kv_b = (const float*)d_in[2];
  const float* w_z_a = (const float*)d_in[3];
  const float* w_z_b = (const float*)d_in[4];
  const float* b_a = (const float*)d_in[5];
  const float* b_b = (const float*)d_in[6];
  u16* Wt = (u16*)d_ws;  // 2 MB frag-ordered bf16 weights
  float* out = (float*)d_out;
  wconv_kernel<<<128, 256, 0, stream>>>(w_kv_a, w_kv_b, w_z_a, w_z_b, Wt);
  fused_kernel<<<256, NTHREADS, 0, stream>>>(h, Wt, b_a, b_b, out);
}